// Round 21
// baseline (1067.309 us; speedup 1.0000x reference)
//
#include <hip/hip_runtime.h>
#include <stdint.h>

#define B_ 8
#define S_ 4096
#define D_ 192
#define M_ (B_*S_)

typedef short v8s __attribute__((ext_vector_type(8)));
typedef float v4f __attribute__((ext_vector_type(4)));
typedef unsigned short v4us __attribute__((ext_vector_type(4)));
typedef unsigned long long ull;

static __device__ __forceinline__ unsigned short f2bf(float f){
  union{float f; unsigned u;} v; v.f=f;
  unsigned u = v.u;
  unsigned r = (u + 0x7fffu + ((u>>16)&1u))>>16;
  return (unsigned short)r;
}
static __device__ __forceinline__ float bf2f(short s){
  union{unsigned u; float f;} v; v.u = ((unsigned)(unsigned short)s)<<16; return v.f;
}
static __device__ __forceinline__ float fexp2(float x){
  return __builtin_amdgcn_exp2f(x);
}
static __device__ __forceinline__ unsigned cvtpk(float lo, float hi){
  unsigned r;
  asm("v_cvt_pk_bf16_f32 %0, %1, %2" : "=v"(r) : "v"(lo), "v"(hi));
  return r;
}

// ---- fp8 e4m3fn pack ----
static __device__ __forceinline__ unsigned sw_fp8(float x){
  union{float f; unsigned u;} v; v.f = x;
  unsigned s = (v.u >> 24) & 0x80u;
  float a = fabsf(x);
  if (a < 0.001953125f) return s;
  if (a >= 240.f) return s | 0x7Eu;
  if (a < 0.015625f) {
    int m = (int)(a*512.f + 0.5f); if(m>7) m=7;
    return s | (unsigned)m;
  }
  int e = (int)((v.u >> 23) & 0xff) - 127;
  unsigned mant = (v.u >> 20) & 0x7u;
  unsigned rest = v.u & 0xFFFFFu;
  if (rest > 0x80000u || (rest == 0x80000u && (mant&1u))) mant++;
  unsigned ee = (unsigned)(e + 7);
  if (mant == 8u){ mant = 0u; ee++; }
  return s | (ee<<3) | mant;
}
template<bool HI>
static __device__ __forceinline__ unsigned pk8(float a, float b, unsigned old){
#if __has_builtin(__builtin_amdgcn_cvt_pk_fp8_f32)
  return __builtin_amdgcn_cvt_pk_fp8_f32(a, b, old, HI);
#else
  unsigned p = sw_fp8(a) | (sw_fp8(b)<<8);
  return HI ? ((old & 0x0000FFFFu) | (p<<16)) : ((old & 0xFFFF0000u) | p);
#endif
}

typedef const __attribute__((address_space(1))) unsigned int gu32;
typedef __attribute__((address_space(3))) unsigned int lu32;
#define GLL16(gp, lp) __builtin_amdgcn_global_load_lds((gu32*)(gp), (lu32*)(lp), 16, 0, 0)

// ---------------- weight conversion fp32 -> bf16 ----------------
__global__ void cvt_w_kernel(const float* w0,const float* w1,const float* w2,const float* w3,
                             const float* w4,const float* w5,const float* w6,const float* w7,
                             unsigned short* dst){
  int w = blockIdx.y;
  const float* src;
  switch(w){
    case 0: src=w0; break; case 1: src=w1; break; case 2: src=w2; break; case 3: src=w3; break;
    case 4: src=w4; break; case 5: src=w5; break; case 6: src=w6; break; default: src=w7; break;
  }
  int i = blockIdx.x*256 + threadIdx.x;
  float v = src[i];
  if(w==0 || w==4 || w==1 || w==5) v *= 0.32267249f;   // sqrt(log2(e)/sqrt(192))
  dst[(size_t)w*36864 + i] = f2bf(v);
}

// ---------------- fused QKV projection ----------------
// Outputs: Q8,K8 fp8 [row][192] bytes; V bf16 TRANSPOSED [b][d][S].
__global__ __launch_bounds__(256) void proj_kernel(
    const float* __restrict__ x, const unsigned short* __restrict__ Wb,
    unsigned char* __restrict__ QK8, unsigned short* __restrict__ V16)
{
  __shared__ __align__(16) unsigned short Vstage[192*72];   // 27.6 KB
  const size_t MDB = (size_t)M_*D_;
  const size_t MD  = (size_t)M_*D_;
  int tid = threadIdx.x;
  int wid = tid>>6, lane = tid&63;
  int lr = lane&15, lg = lane>>4, kb = lg*8;
  int m0 = blockIdx.x*64 + wid*16;
  int row = m0 + lr;

  v8s a[6];
  #pragma unroll
  for(int c=0;c<6;c++){
    const float* xp = &x[(size_t)row*D_ + c*32 + kb];
    float4 f0 = *(const float4*)xp;
    float4 f1 = *(const float4*)(xp+4);
    v8s t;
    t[0]=(short)f2bf(f0.x); t[1]=(short)f2bf(f0.y); t[2]=(short)f2bf(f0.z); t[3]=(short)f2bf(f0.w);
    t[4]=(short)f2bf(f1.x); t[5]=(short)f2bf(f1.y); t[6]=(short)f2bf(f1.z); t[7]=(short)f2bf(f1.w);
    a[c]=t;
  }
  int bidx = m0 / S_;
  int sb   = (blockIdx.x*64) % S_;
  int sloc = wid*16 + lg*4;

  for(int path=0; path<2; path++){
    unsigned char* dstQ8 = QK8 + (size_t)path*2*MDB;
    for(int which=0; which<2; which++){
      const unsigned short* W = Wb + (size_t)(path*4 + which)*36864;
      unsigned char* dst = which==0 ? dstQ8 : dstQ8 + MDB;
      #pragma unroll
      for(int nt=0; nt<12; nt++){
        v4f acc = {0.f,0.f,0.f,0.f};
        int n = nt*16 + lr;
        #pragma unroll
        for(int c=0;c<6;c++){
          v8s bfr = *(const v8s*)&W[(size_t)n*D_ + c*32 + kb];
          acc = __builtin_amdgcn_mfma_f32_16x16x32_bf16(a[c], bfr, acc, 0,0,0);
        }
        int col = nt*16 + lr;
        int r0 = m0 + lg*4;
        #pragma unroll
        for(int r=0;r<4;r++){
          unsigned p = pk8<false>(acc[r], 0.f, 0u);
          dst[(size_t)(r0+r)*D_ + col] = (unsigned char)(p & 0xFF);
        }
      }
    }
    // V -> bf16 LDS transpose stage -> coalesced stores
    {
      const unsigned short* W = Wb + (size_t)(path*4 + 2)*36864;
      #pragma unroll
      for(int nt=0; nt<12; nt++){
        v4f acc = {0.f,0.f,0.f,0.f};
        int n = nt*16 + lr;
        #pragma unroll
        for(int c=0;c<6;c++){
          v8s bfr = *(const v8s*)&W[(size_t)n*D_ + c*32 + kb];
          acc = __builtin_amdgcn_mfma_f32_16x16x32_bf16(a[c], bfr, acc, 0,0,0);
        }
        int col = nt*16 + lr;
        v4us pk;
        pk[0]=f2bf(acc[0]); pk[1]=f2bf(acc[1]); pk[2]=f2bf(acc[2]); pk[3]=f2bf(acc[3]);
        *(v4us*)&Vstage[col*72 + sloc] = pk;
      }
      __syncthreads();
      unsigned short* dstV = V16 + (size_t)path*MD;
      size_t vg = (size_t)bidx*D_*S_ + sb;
      #pragma unroll
      for(int j=0;j<6;j++){
        int i = tid + j*256;
        int d = i>>3, s8 = (i&7)*8;
        *(v8s*)&dstV[vg + (size_t)d*S_ + s8] = *(const v8s*)&Vstage[d*72 + s8];
      }
      __syncthreads();
    }
  }
}

// ---------------- flash attention: split-K halves, 4 blocks/CU ----------
// grid dim3(64,8,2) = 1024 blocks (2 KV-halves x 32 q-blocks x 8 b x 2 paths).
// Static softmax (m==0) => partials combine linearly; each block stores raw
// (unnormalized) O-partial bf16 + per-row lsum fp32. 256 thr, 4w x 32 q-rows.
// K fp8 reg-staged (200B rows, conflict-free); V bf16 DMA+swizzle; fp8 QK,
// bf16 PV, cvtpk+permlane P.
#define KSTR8 200

__global__ __launch_bounds__(256,4) void attn_kernel(
    const unsigned char* __restrict__ QK8,
    const unsigned short* __restrict__ V16,
    unsigned short* __restrict__ Ob,
    float* __restrict__ Ls)
{
  __shared__ __align__(16) unsigned char  KL[2][32*KSTR8];   // 2 x 6.25 KB
  __shared__ __align__(16) unsigned short VL[2][192*32];     // 2 x 12 KB (37 KB)

  int flat = blockIdx.x + 64*blockIdx.y + 512*blockIdx.z;
  int w = (flat&7)*128 + (flat>>3);   // bijective on [0,1024)
  int qi   =  w        & 31;
  int b    = (w>>5)    & 7;
  int z    = (w>>8)    & 1;
  int half = (w>>9)    & 1;           // top bit: XCD keeps 2.25MB KV set

  const size_t MDB = (size_t)M_*D_;
  const unsigned char* Q8 = QK8 + (size_t)z*2*MDB;
  const unsigned char* K8 = Q8 + MDB;
  const unsigned short* Vt = V16 + (size_t)z*M_*D_;
  unsigned short* O = Ob + (size_t)(z*2+half)*MDB;
  float* Lp = Ls + (size_t)(z*2+half)*M_;

  int q0 = qi*128;
  int tid = threadIdx.x, wid=tid>>6, lane=tid&63;
  int lr = lane&15, lg = lane>>4;
  size_t bK = (size_t)b*S_*D_;        // bytes (fp8)
  size_t bV = (size_t)b*D_*S_;        // shorts
  int qrow0 = q0 + wid*32;

  int ksR = tid>>3, ksC = (tid&7)*24;
  int kLds = ksR*KSTR8 + ksC;
  int voff[3], vLds[3];
  #pragma unroll
  for(int j=0;j<3;j++){
    int i = tid + j*256;
    int vrow = i>>2, vin = (i&3)*16;
    voff[j] = vrow*4096 + ((vin ^ (((vrow>>1)&3)<<4))>>1);
    vLds[j] = i*16;
  }
  int vro = ((lg*16) ^ (((lr>>1)&3)<<4)) >> 1;

  long qf8[2][6];
  #pragma unroll
  for(int h=0;h<2;h++){
    const unsigned char* qp = Q8 + bK + (size_t)(qrow0 + h*16 + lr)*D_;
    #pragma unroll
    for(int c=0;c<6;c++) qf8[h][c] = *(const long*)(qp + c*32 + lg*8);
  }
  float lsum[2] = {0.f, 0.f};
  v4f oacc[2][12];
  #pragma unroll
  for(int h=0;h<2;h++)
    #pragma unroll
    for(int e=0;e<12;e++) oacc[h][e] = (v4f){0.f,0.f,0.f,0.f};

  ull kreg0, kreg1, kreg2;
  auto kissue = [&](int t){
    const unsigned char* kg = K8 + bK + (size_t)t*6144 + ksR*192 + ksC;
    kreg0 = *(const ull*)(kg);
    kreg1 = *(const ull*)(kg+8);
    kreg2 = *(const ull*)(kg+16);
  };
  auto kwrite = [&](int buf){
    unsigned char* d = &KL[buf][kLds];
    *(ull*)(d)    = kreg0;
    *(ull*)(d+8)  = kreg1;
    *(ull*)(d+16) = kreg2;
  };
  auto vissue = [&](int t, int buf){
    const unsigned short* vg = Vt + bV + (size_t)t*32;
    #pragma unroll
    for(int j=0;j<3;j++) GLL16(vg + voff[j], ((unsigned char*)&VL[buf][0]) + vLds[j]);
  };
  auto do_qk = [&](int kcur, v4f sacc[2][2]){
    __builtin_amdgcn_s_setprio(1);
    #pragma unroll
    for(int ct=0; ct<2; ct++){
      v4f s0 = {0.f,0.f,0.f,0.f}, s1 = {0.f,0.f,0.f,0.f};
      const unsigned char* rb = &KL[kcur][(ct*16+lr)*KSTR8];
      #pragma unroll
      for(int c=0;c<6;c++){
        long kf8 = *(const long*)(rb + c*32 + lg*8);
        s0 = __builtin_amdgcn_mfma_f32_16x16x32_fp8_fp8(kf8, qf8[0][c], s0, 0,0,0);
        s1 = __builtin_amdgcn_mfma_f32_16x16x32_fp8_fp8(kf8, qf8[1][c], s1, 0,0,0);
      }
      sacc[0][ct]=s0; sacc[1][ct]=s1;
    }
    __builtin_amdgcn_s_setprio(0);
  };
  auto do_softmax = [&](v4f sacc[2][2], v8s pa[2]){
    #pragma unroll
    for(int h=0;h<2;h++){
      float p00=fexp2(sacc[h][0][0]), p01=fexp2(sacc[h][0][1]);
      float p02=fexp2(sacc[h][0][2]), p03=fexp2(sacc[h][0][3]);
      float p10=fexp2(sacc[h][1][0]), p11=fexp2(sacc[h][1][1]);
      float p12=fexp2(sacc[h][1][2]), p13=fexp2(sacc[h][1][3]);
      lsum[h] += ((p00+p01)+(p02+p03)) + ((p10+p11)+(p12+p13));
      unsigned X0=cvtpk(p00,p01), X1=cvtpk(p02,p03);
      unsigned Y0=cvtpk(p10,p11), Y1=cvtpk(p12,p13);
      asm("v_permlane32_swap_b32 %0, %1" : "+v"(Y0), "+v"(X0));
      asm("v_permlane32_swap_b32 %0, %1" : "+v"(Y1), "+v"(X1));
      asm("v_permlane16_swap_b32 %0, %1" : "+v"(Y0), "+v"(X0));
      asm("v_permlane16_swap_b32 %0, %1" : "+v"(Y1), "+v"(X1));
      union{ v8s s; unsigned w[4]; } u;
      u.w[0] = X0;  u.w[1] = X1;  u.w[2] = Y0;  u.w[3] = Y1;
      pa[h] = u.s;
    }
  };
  auto do_pv = [&](int vcur, v8s pa[2]){
    __builtin_amdgcn_s_setprio(1);
    #pragma unroll
    for(int e=0;e<12;e++){
      v8s vbf = *(const v8s*)&VL[vcur][(e*16+lr)*32 + vro];
      oacc[0][e] = __builtin_amdgcn_mfma_f32_16x16x32_bf16(pa[0], vbf, oacc[0][e], 0,0,0);
      oacc[1][e] = __builtin_amdgcn_mfma_f32_16x16x32_bf16(pa[1], vbf, oacc[1][e], 0,0,0);
    }
    __builtin_amdgcn_s_setprio(0);
  };

  int t0 = half*64;
  // prologue: first tile of this half
  kissue(t0);
  vissue(t0, 0);
  kwrite(0);
  asm volatile("s_waitcnt vmcnt(0)" ::: "memory");
  __syncthreads();

  for(int tt=0; tt<64; tt++){
    int t = t0 + tt;
    int cur = tt&1;
    if(tt<63){ kissue(t+1); vissue(t+1, cur^1); }
    __builtin_amdgcn_sched_barrier(0);

    v4f sacc[2][2];
    do_qk(cur, sacc);
    v8s pa[2];
    do_softmax(sacc, pa);
    do_pv(cur, pa);

    if(tt<63) kwrite(cur^1);
    asm volatile("s_waitcnt vmcnt(0)" ::: "memory");
    __syncthreads();
  }

  // epilogue: store per-row lsum partial (fp32) + raw O partial (bf16)
  #pragma unroll
  for(int h=0;h<2;h++){
    float ps = lsum[h];
    ps += __shfl_xor(ps, 16);
    ps += __shfl_xor(ps, 32);
    if(lane < 16){
      Lp[(size_t)b*S_ + qrow0 + h*16 + lr] = ps;
    }
  }
  #pragma unroll
  for(int h=0;h<2;h++){
    size_t orow0 = ((size_t)b*S_ + qrow0 + h*16 + lg*4)*D_;
    #pragma unroll
    for(int e=0;e<12;e++){
      #pragma unroll
      for(int r=0;r<4;r++){
        O[orow0 + (size_t)r*D_ + e*16 + lr] = f2bf(oacc[h][e][r]);
      }
    }
  }
}

// ---------------- final: combine halves, R = O @ Wo^T, combine, fixes ------
__global__ __launch_bounds__(256) void final_kernel(
  const float* __restrict__ x,
  const unsigned short* __restrict__ Ob,
  const float* __restrict__ Ls,
  const unsigned short* __restrict__ WoR,
  const unsigned short* __restrict__ WoW,
  float* __restrict__ out)
{
  const size_t MD = (size_t)M_*D_;
  int tid=threadIdx.x, wid=tid>>6, lane=tid&63;
  int lr=lane&15, lg=lane>>4, kb=lg*8;
  int m0 = blockIdx.x*64 + wid*16;
  int arow = m0 + lr;

  v8s ar[6], aw[6];
  #pragma unroll
  for(int path=0; path<2; path++){
    const unsigned short* O0 = Ob + (size_t)path*2*MD;
    const unsigned short* O1 = O0 + MD;
    const float* L0 = Ls + (size_t)path*2*M_;
    const float* L1 = L0 + M_;
    float inv = 1.0f/(L0[arow] + L1[arow]);
    #pragma unroll
    for(int c=0;c<6;c++){
      v8s x0 = *(const v8s*)&O0[(size_t)arow*D_ + c*32 + kb];
      v8s x1 = *(const v8s*)&O1[(size_t)arow*D_ + c*32 + kb];
      v8s t;
      #pragma unroll
      for(int j=0;j<8;j++){
        float f = (bf2f(x0[j]) + bf2f(x1[j])) * inv;
        t[j] = (short)f2bf(f);
      }
      if(path==0) ar[c]=t; else aw[c]=t;
    }
  }

  int bidx = m0 / S_;
  float rf = x[(size_t)bidx*S_*D_ + 156];
  float wf = x[(size_t)bidx*S_*D_ + 157];
  #pragma unroll
  for(int nt=0; nt<12; nt++){
    v4f accR={0.f,0.f,0.f,0.f}, accW={0.f,0.f,0.f,0.f};
    int n = nt*16 + lr;
    #pragma unroll
    for(int c=0;c<6;c++){
      v8s br = *(const v8s*)&WoR[(size_t)n*D_ + c*32 + kb];
      accR = __builtin_amdgcn_mfma_f32_16x16x32_bf16(ar[c], br, accR,0,0,0);
      v8s bw = *(const v8s*)&WoW[(size_t)n*D_ + c*32 + kb];
      accW = __builtin_amdgcn_mfma_f32_16x16x32_bf16(aw[c], bw, accW,0,0,0);
    }
    #pragma unroll
    for(int r=0;r<4;r++){
      int row = m0 + lg*4 + r;
      int col = nt*16 + lr;
      float xv = x[(size_t)row*D_ + col];
      float val = xv + rf*(accR[r]-xv) + wf*(accW[r]-xv);
      if(col==156||col==157) val = 0.f;
      else if(col==158) val = rf+wf;
      out[(size_t)row*D_ + col] = val;
    }
  }
}

extern "C" void kernel_launch(void* const* d_in, const int* in_sizes, int n_in,
                              void* d_out, int out_size, void* d_ws, size_t ws_size,
                              hipStream_t stream) {
  const float* x = (const float*)d_in[0];
  char* wsb = (char*)d_ws;
  const size_t WSZ = 36864;
  const size_t MDB = (size_t)M_*D_;
  unsigned short* Wb  = (unsigned short*)wsb;                        // 0.59 MB
  unsigned char*  QK8 = (unsigned char*)(wsb + 8*WSZ*2);             // 25.2 MB
  unsigned short* V16 = (unsigned short*)(wsb + 8*WSZ*2 + 4*MDB);    // 50.3 MB
  unsigned short* Ob  = V16 + 2*MDB;                                 // 4 x MD bf16 = 50.3 MB
  float*          Ls  = (float*)(Ob + 4*MDB);                        // 4 x M fp32 = 0.5 MB

  cvt_w_kernel<<<dim3(144,8),256,0,stream>>>(
      (const float*)d_in[1],(const float*)d_in[2],(const float*)d_in[3],(const float*)d_in[4],
      (const float*)d_in[5],(const float*)d_in[6],(const float*)d_in[7],(const float*)d_in[8], Wb);

  proj_kernel<<<512,256,0,stream>>>(x, Wb, QK8, V16);
  attn_kernel<<<dim3(64,8,2),256,0,stream>>>(QK8, V16, Ob, Ls);
  final_kernel<<<512,256,0,stream>>>(x, Ob, Ls,
                                     Wb+3*WSZ, Wb+7*WSZ, (float*)d_out);
}

// Round 22
// 351.104 us; speedup vs baseline: 3.0399x; 3.0399x over previous
//
#include <hip/hip_runtime.h>
#include <stdint.h>

#define B_ 8
#define S_ 4096
#define D_ 192
#define M_ (B_*S_)

typedef short v8s __attribute__((ext_vector_type(8)));
typedef float v4f __attribute__((ext_vector_type(4)));
typedef unsigned short v4us __attribute__((ext_vector_type(4)));
typedef unsigned long long ull;

static __device__ __forceinline__ unsigned short f2bf(float f){
  union{float f; unsigned u;} v; v.f=f;
  unsigned u = v.u;
  unsigned r = (u + 0x7fffu + ((u>>16)&1u))>>16;
  return (unsigned short)r;
}
static __device__ __forceinline__ float bf2f(short s){
  union{unsigned u; float f;} v; v.u = ((unsigned)(unsigned short)s)<<16; return v.f;
}
static __device__ __forceinline__ float fexp2(float x){
  return __builtin_amdgcn_exp2f(x);
}
static __device__ __forceinline__ unsigned cvtpk(float lo, float hi){
  unsigned r;
  asm("v_cvt_pk_bf16_f32 %0, %1, %2" : "=v"(r) : "v"(lo), "v"(hi));
  return r;
}

// ---- fp8 e4m3fn pack ----
static __device__ __forceinline__ unsigned sw_fp8(float x){
  union{float f; unsigned u;} v; v.f = x;
  unsigned s = (v.u >> 24) & 0x80u;
  float a = fabsf(x);
  if (a < 0.001953125f) return s;
  if (a >= 240.f) return s | 0x7Eu;
  if (a < 0.015625f) {
    int m = (int)(a*512.f + 0.5f); if(m>7) m=7;
    return s | (unsigned)m;
  }
  int e = (int)((v.u >> 23) & 0xff) - 127;
  unsigned mant = (v.u >> 20) & 0x7u;
  unsigned rest = v.u & 0xFFFFFu;
  if (rest > 0x80000u || (rest == 0x80000u && (mant&1u))) mant++;
  unsigned ee = (unsigned)(e + 7);
  if (mant == 8u){ mant = 0u; ee++; }
  return s | (ee<<3) | mant;
}
template<bool HI>
static __device__ __forceinline__ unsigned pk8(float a, float b, unsigned old){
#if __has_builtin(__builtin_amdgcn_cvt_pk_fp8_f32)
  return __builtin_amdgcn_cvt_pk_fp8_f32(a, b, old, HI);
#else
  unsigned p = sw_fp8(a) | (sw_fp8(b)<<8);
  return HI ? ((old & 0x0000FFFFu) | (p<<16)) : ((old & 0xFFFF0000u) | p);
#endif
}

typedef const __attribute__((address_space(1))) unsigned int gu32;
typedef __attribute__((address_space(3))) unsigned int lu32;
#define GLL16(gp, lp) __builtin_amdgcn_global_load_lds((gu32*)(gp), (lu32*)(lp), 16, 0, 0)

// ---------------- weight conversion fp32 -> bf16 ----------------
__global__ void cvt_w_kernel(const float* w0,const float* w1,const float* w2,const float* w3,
                             const float* w4,const float* w5,const float* w6,const float* w7,
                             unsigned short* dst){
  int w = blockIdx.y;
  const float* src;
  switch(w){
    case 0: src=w0; break; case 1: src=w1; break; case 2: src=w2; break; case 3: src=w3; break;
    case 4: src=w4; break; case 5: src=w5; break; case 6: src=w6; break; default: src=w7; break;
  }
  int i = blockIdx.x*256 + threadIdx.x;
  float v = src[i];
  if(w==0 || w==4 || w==1 || w==5) v *= 0.32267249f;   // sqrt(log2(e)/sqrt(192))
  dst[(size_t)w*36864 + i] = f2bf(v);
}

// ---------------- fused QKV projection ----------------
// Outputs: Q8,K8 fp8 [row][192] bytes; V bf16 TRANSPOSED [b][d][S].
__global__ __launch_bounds__(256) void proj_kernel(
    const float* __restrict__ x, const unsigned short* __restrict__ Wb,
    unsigned char* __restrict__ QK8, unsigned short* __restrict__ V16)
{
  __shared__ __align__(16) unsigned short Vstage[192*72];   // 27.6 KB
  const size_t MDB = (size_t)M_*D_;
  const size_t MD  = (size_t)M_*D_;
  int tid = threadIdx.x;
  int wid = tid>>6, lane = tid&63;
  int lr = lane&15, lg = lane>>4, kb = lg*8;
  int m0 = blockIdx.x*64 + wid*16;
  int row = m0 + lr;

  v8s a[6];
  #pragma unroll
  for(int c=0;c<6;c++){
    const float* xp = &x[(size_t)row*D_ + c*32 + kb];
    float4 f0 = *(const float4*)xp;
    float4 f1 = *(const float4*)(xp+4);
    v8s t;
    t[0]=(short)f2bf(f0.x); t[1]=(short)f2bf(f0.y); t[2]=(short)f2bf(f0.z); t[3]=(short)f2bf(f0.w);
    t[4]=(short)f2bf(f1.x); t[5]=(short)f2bf(f1.y); t[6]=(short)f2bf(f1.z); t[7]=(short)f2bf(f1.w);
    a[c]=t;
  }
  int bidx = m0 / S_;
  int sb   = (blockIdx.x*64) % S_;
  int sloc = wid*16 + lg*4;

  for(int path=0; path<2; path++){
    unsigned char* dstQ8 = QK8 + (size_t)path*2*MDB;
    for(int which=0; which<2; which++){
      const unsigned short* W = Wb + (size_t)(path*4 + which)*36864;
      unsigned char* dst = which==0 ? dstQ8 : dstQ8 + MDB;
      #pragma unroll
      for(int nt=0; nt<12; nt++){
        v4f acc = {0.f,0.f,0.f,0.f};
        int n = nt*16 + lr;
        #pragma unroll
        for(int c=0;c<6;c++){
          v8s bfr = *(const v8s*)&W[(size_t)n*D_ + c*32 + kb];
          acc = __builtin_amdgcn_mfma_f32_16x16x32_bf16(a[c], bfr, acc, 0,0,0);
        }
        int col = nt*16 + lr;
        int r0 = m0 + lg*4;
        #pragma unroll
        for(int r=0;r<4;r++){
          unsigned p = pk8<false>(acc[r], 0.f, 0u);
          dst[(size_t)(r0+r)*D_ + col] = (unsigned char)(p & 0xFF);
        }
      }
    }
    // V -> bf16 LDS transpose stage -> coalesced stores
    {
      const unsigned short* W = Wb + (size_t)(path*4 + 2)*36864;
      #pragma unroll
      for(int nt=0; nt<12; nt++){
        v4f acc = {0.f,0.f,0.f,0.f};
        int n = nt*16 + lr;
        #pragma unroll
        for(int c=0;c<6;c++){
          v8s bfr = *(const v8s*)&W[(size_t)n*D_ + c*32 + kb];
          acc = __builtin_amdgcn_mfma_f32_16x16x32_bf16(a[c], bfr, acc, 0,0,0);
        }
        int col = nt*16 + lr;
        v4us pk;
        pk[0]=f2bf(acc[0]); pk[1]=f2bf(acc[1]); pk[2]=f2bf(acc[2]); pk[3]=f2bf(acc[3]);
        *(v4us*)&Vstage[col*72 + sloc] = pk;
      }
      __syncthreads();
      unsigned short* dstV = V16 + (size_t)path*MD;
      size_t vg = (size_t)bidx*D_*S_ + sb;
      #pragma unroll
      for(int j=0;j<6;j++){
        int i = tid + j*256;
        int d = i>>3, s8 = (i&7)*8;
        *(v8s*)&dstV[vg + (size_t)d*S_ + s8] = *(const v8s*)&Vstage[d*72 + s8];
      }
      __syncthreads();
    }
  }
}

// ---------------- flash attention: split-K halves, 3 blocks/CU ----------
// grid dim3(64,8,2) = 1024 blocks (2 KV-halves x 32 q-blocks x 8 b x 2 paths).
// launch_bounds (256,3): round-20-proven register budget (84 VGPR + acc, NO
// spill); grid 1024 now allows 3 blocks/CU (was grid-capped at 2).
// Static softmax (m==0) => partials combine linearly; block stores raw
// O-partial bf16 + per-row lsum fp32. K fp8 reg-staged (200B rows), V bf16
// DMA+swizzle, fp8 QK, bf16 PV, cvtpk+permlane P.
#define KSTR8 200

__global__ __launch_bounds__(256,3) void attn_kernel(
    const unsigned char* __restrict__ QK8,
    const unsigned short* __restrict__ V16,
    unsigned short* __restrict__ Ob,
    float* __restrict__ Ls)
{
  __shared__ __align__(16) unsigned char  KL[2][32*KSTR8];   // 2 x 6.25 KB
  __shared__ __align__(16) unsigned short VL[2][192*32];     // 2 x 12 KB (37 KB)

  int flat = blockIdx.x + 64*blockIdx.y + 512*blockIdx.z;
  int w = (flat&7)*128 + (flat>>3);   // bijective on [0,1024)
  int qi   =  w        & 31;
  int b    = (w>>5)    & 7;
  int z    = (w>>8)    & 1;
  int half = (w>>9)    & 1;           // top bit: XCD keeps 2.25MB KV set

  const size_t MDB = (size_t)M_*D_;
  const unsigned char* Q8 = QK8 + (size_t)z*2*MDB;
  const unsigned char* K8 = Q8 + MDB;
  const unsigned short* Vt = V16 + (size_t)z*M_*D_;
  unsigned short* O = Ob + (size_t)(z*2+half)*MDB;
  float* Lp = Ls + (size_t)(z*2+half)*M_;

  int q0 = qi*128;
  int tid = threadIdx.x, wid=tid>>6, lane=tid&63;
  int lr = lane&15, lg = lane>>4;
  size_t bK = (size_t)b*S_*D_;        // bytes (fp8)
  size_t bV = (size_t)b*D_*S_;        // shorts
  int qrow0 = q0 + wid*32;

  int ksR = tid>>3, ksC = (tid&7)*24;
  int kLds = ksR*KSTR8 + ksC;
  int voff[3], vLds[3];
  #pragma unroll
  for(int j=0;j<3;j++){
    int i = tid + j*256;
    int vrow = i>>2, vin = (i&3)*16;
    voff[j] = vrow*4096 + ((vin ^ (((vrow>>1)&3)<<4))>>1);
    vLds[j] = i*16;
  }
  int vro = ((lg*16) ^ (((lr>>1)&3)<<4)) >> 1;

  long qf8[2][6];
  #pragma unroll
  for(int h=0;h<2;h++){
    const unsigned char* qp = Q8 + bK + (size_t)(qrow0 + h*16 + lr)*D_;
    #pragma unroll
    for(int c=0;c<6;c++) qf8[h][c] = *(const long*)(qp + c*32 + lg*8);
  }
  float lsum[2] = {0.f, 0.f};
  v4f oacc[2][12];
  #pragma unroll
  for(int h=0;h<2;h++)
    #pragma unroll
    for(int e=0;e<12;e++) oacc[h][e] = (v4f){0.f,0.f,0.f,0.f};

  ull kreg0, kreg1, kreg2;
  auto kissue = [&](int t){
    const unsigned char* kg = K8 + bK + (size_t)t*6144 + ksR*192 + ksC;
    kreg0 = *(const ull*)(kg);
    kreg1 = *(const ull*)(kg+8);
    kreg2 = *(const ull*)(kg+16);
  };
  auto kwrite = [&](int buf){
    unsigned char* d = &KL[buf][kLds];
    *(ull*)(d)    = kreg0;
    *(ull*)(d+8)  = kreg1;
    *(ull*)(d+16) = kreg2;
  };
  auto vissue = [&](int t, int buf){
    const unsigned short* vg = Vt + bV + (size_t)t*32;
    #pragma unroll
    for(int j=0;j<3;j++) GLL16(vg + voff[j], ((unsigned char*)&VL[buf][0]) + vLds[j]);
  };
  auto do_qk = [&](int kcur, v4f sacc[2][2]){
    __builtin_amdgcn_s_setprio(1);
    #pragma unroll
    for(int ct=0; ct<2; ct++){
      v4f s0 = {0.f,0.f,0.f,0.f}, s1 = {0.f,0.f,0.f,0.f};
      const unsigned char* rb = &KL[kcur][(ct*16+lr)*KSTR8];
      #pragma unroll
      for(int c=0;c<6;c++){
        long kf8 = *(const long*)(rb + c*32 + lg*8);
        s0 = __builtin_amdgcn_mfma_f32_16x16x32_fp8_fp8(kf8, qf8[0][c], s0, 0,0,0);
        s1 = __builtin_amdgcn_mfma_f32_16x16x32_fp8_fp8(kf8, qf8[1][c], s1, 0,0,0);
      }
      sacc[0][ct]=s0; sacc[1][ct]=s1;
    }
    __builtin_amdgcn_s_setprio(0);
  };
  auto do_softmax = [&](v4f sacc[2][2], v8s pa[2]){
    #pragma unroll
    for(int h=0;h<2;h++){
      float p00=fexp2(sacc[h][0][0]), p01=fexp2(sacc[h][0][1]);
      float p02=fexp2(sacc[h][0][2]), p03=fexp2(sacc[h][0][3]);
      float p10=fexp2(sacc[h][1][0]), p11=fexp2(sacc[h][1][1]);
      float p12=fexp2(sacc[h][1][2]), p13=fexp2(sacc[h][1][3]);
      lsum[h] += ((p00+p01)+(p02+p03)) + ((p10+p11)+(p12+p13));
      unsigned X0=cvtpk(p00,p01), X1=cvtpk(p02,p03);
      unsigned Y0=cvtpk(p10,p11), Y1=cvtpk(p12,p13);
      asm("v_permlane32_swap_b32 %0, %1" : "+v"(Y0), "+v"(X0));
      asm("v_permlane32_swap_b32 %0, %1" : "+v"(Y1), "+v"(X1));
      asm("v_permlane16_swap_b32 %0, %1" : "+v"(Y0), "+v"(X0));
      asm("v_permlane16_swap_b32 %0, %1" : "+v"(Y1), "+v"(X1));
      union{ v8s s; unsigned w[4]; } u;
      u.w[0] = X0;  u.w[1] = X1;  u.w[2] = Y0;  u.w[3] = Y1;
      pa[h] = u.s;
    }
  };
  auto do_pv = [&](int vcur, v8s pa[2]){
    __builtin_amdgcn_s_setprio(1);
    #pragma unroll
    for(int e=0;e<12;e++){
      v8s vbf = *(const v8s*)&VL[vcur][(e*16+lr)*32 + vro];
      oacc[0][e] = __builtin_amdgcn_mfma_f32_16x16x32_bf16(pa[0], vbf, oacc[0][e], 0,0,0);
      oacc[1][e] = __builtin_amdgcn_mfma_f32_16x16x32_bf16(pa[1], vbf, oacc[1][e], 0,0,0);
    }
    __builtin_amdgcn_s_setprio(0);
  };

  int t0 = half*64;
  // prologue: first tile of this half
  kissue(t0);
  vissue(t0, 0);
  kwrite(0);
  asm volatile("s_waitcnt vmcnt(0)" ::: "memory");
  __syncthreads();

  for(int tt=0; tt<64; tt++){
    int t = t0 + tt;
    int cur = tt&1;
    if(tt<63){ kissue(t+1); vissue(t+1, cur^1); }
    __builtin_amdgcn_sched_barrier(0);

    v4f sacc[2][2];
    do_qk(cur, sacc);
    v8s pa[2];
    do_softmax(sacc, pa);
    do_pv(cur, pa);

    if(tt<63) kwrite(cur^1);
    asm volatile("s_waitcnt vmcnt(0)" ::: "memory");
    __syncthreads();
  }

  // epilogue: store per-row lsum partial (fp32) + raw O partial (bf16)
  #pragma unroll
  for(int h=0;h<2;h++){
    float ps = lsum[h];
    ps += __shfl_xor(ps, 16);
    ps += __shfl_xor(ps, 32);
    if(lane < 16){
      Lp[(size_t)b*S_ + qrow0 + h*16 + lr] = ps;
    }
  }
  #pragma unroll
  for(int h=0;h<2;h++){
    size_t orow0 = ((size_t)b*S_ + qrow0 + h*16 + lg*4)*D_;
    #pragma unroll
    for(int e=0;e<12;e++){
      #pragma unroll
      for(int r=0;r<4;r++){
        O[orow0 + (size_t)r*D_ + e*16 + lr] = f2bf(oacc[h][e][r]);
      }
    }
  }
}

// ---------------- final: combine halves, R = O @ Wo^T, combine, fixes ------
__global__ __launch_bounds__(256) void final_kernel(
  const float* __restrict__ x,
  const unsigned short* __restrict__ Ob,
  const float* __restrict__ Ls,
  const unsigned short* __restrict__ WoR,
  const unsigned short* __restrict__ WoW,
  float* __restrict__ out)
{
  const size_t MD = (size_t)M_*D_;
  int tid=threadIdx.x, wid=tid>>6, lane=tid&63;
  int lr=lane&15, lg=lane>>4, kb=lg*8;
  int m0 = blockIdx.x*64 + wid*16;
  int arow = m0 + lr;

  v8s ar[6], aw[6];
  #pragma unroll
  for(int path=0; path<2; path++){
    const unsigned short* O0 = Ob + (size_t)path*2*MD;
    const unsigned short* O1 = O0 + MD;
    const float* L0 = Ls + (size_t)path*2*M_;
    const float* L1 = L0 + M_;
    float inv = 1.0f/(L0[arow] + L1[arow]);
    #pragma unroll
    for(int c=0;c<6;c++){
      v8s x0 = *(const v8s*)&O0[(size_t)arow*D_ + c*32 + kb];
      v8s x1 = *(const v8s*)&O1[(size_t)arow*D_ + c*32 + kb];
      v8s t;
      #pragma unroll
      for(int j=0;j<8;j++){
        float f = (bf2f(x0[j]) + bf2f(x1[j])) * inv;
        t[j] = (short)f2bf(f);
      }
      if(path==0) ar[c]=t; else aw[c]=t;
    }
  }

  int bidx = m0 / S_;
  float rf = x[(size_t)bidx*S_*D_ + 156];
  float wf = x[(size_t)bidx*S_*D_ + 157];
  #pragma unroll
  for(int nt=0; nt<12; nt++){
    v4f accR={0.f,0.f,0.f,0.f}, accW={0.f,0.f,0.f,0.f};
    int n = nt*16 + lr;
    #pragma unroll
    for(int c=0;c<6;c++){
      v8s br = *(const v8s*)&WoR[(size_t)n*D_ + c*32 + kb];
      accR = __builtin_amdgcn_mfma_f32_16x16x32_bf16(ar[c], br, accR,0,0,0);
      v8s bw = *(const v8s*)&WoW[(size_t)n*D_ + c*32 + kb];
      accW = __builtin_amdgcn_mfma_f32_16x16x32_bf16(aw[c], bw, accW,0,0,0);
    }
    #pragma unroll
    for(int r=0;r<4;r++){
      int row = m0 + lg*4 + r;
      int col = nt*16 + lr;
      float xv = x[(size_t)row*D_ + col];
      float val = xv + rf*(accR[r]-xv) + wf*(accW[r]-xv);
      if(col==156||col==157) val = 0.f;
      else if(col==158) val = rf+wf;
      out[(size_t)row*D_ + col] = val;
    }
  }
}

extern "C" void kernel_launch(void* const* d_in, const int* in_sizes, int n_in,
                              void* d_out, int out_size, void* d_ws, size_t ws_size,
                              hipStream_t stream) {
  const float* x = (const float*)d_in[0];
  char* wsb = (char*)d_ws;
  const size_t WSZ = 36864;
  const size_t MDB = (size_t)M_*D_;
  unsigned short* Wb  = (unsigned short*)wsb;                        // 0.59 MB
  unsigned char*  QK8 = (unsigned char*)(wsb + 8*WSZ*2);             // 25.2 MB
  unsigned short* V16 = (unsigned short*)(wsb + 8*WSZ*2 + 4*MDB);    // 50.3 MB
  unsigned short* Ob  = V16 + 2*MDB;                                 // 4 x MD bf16 = 50.3 MB
  float*          Ls  = (float*)(Ob + 4*MDB);                        // 4 x M fp32 = 0.5 MB

  cvt_w_kernel<<<dim3(144,8),256,0,stream>>>(
      (const float*)d_in[1],(const float*)d_in[2],(const float*)d_in[3],(const float*)d_in[4],
      (const float*)d_in[5],(const float*)d_in[6],(const float*)d_in[7],(const float*)d_in[8], Wb);

  proj_kernel<<<512,256,0,stream>>>(x, Wb, QK8, V16);
  attn_kernel<<<dim3(64,8,2),256,0,stream>>>(QK8, V16, Ob, Ls);
  final_kernel<<<512,256,0,stream>>>(x, Ob, Ls,
                                     Wb+3*WSZ, Wb+7*WSZ, (float*)d_out);
}

// Round 23
// 335.132 us; speedup vs baseline: 3.1847x; 1.0477x over previous
//
#include <hip/hip_runtime.h>
#include <stdint.h>

#define B_ 8
#define S_ 4096
#define D_ 192
#define M_ (B_*S_)

typedef short v8s __attribute__((ext_vector_type(8)));
typedef float v4f __attribute__((ext_vector_type(4)));
typedef unsigned short v4us __attribute__((ext_vector_type(4)));
typedef unsigned long long ull;

static __device__ __forceinline__ unsigned short f2bf(float f){
  union{float f; unsigned u;} v; v.f=f;
  unsigned u = v.u;
  unsigned r = (u + 0x7fffu + ((u>>16)&1u))>>16;
  return (unsigned short)r;
}
static __device__ __forceinline__ float fexp2(float x){
  return __builtin_amdgcn_exp2f(x);
}
static __device__ __forceinline__ unsigned cvtpk(float lo, float hi){
  unsigned r;
  asm("v_cvt_pk_bf16_f32 %0, %1, %2" : "=v"(r) : "v"(lo), "v"(hi));
  return r;
}

// ---- fp8 e4m3fn pack ----
static __device__ __forceinline__ unsigned sw_fp8(float x){
  union{float f; unsigned u;} v; v.f = x;
  unsigned s = (v.u >> 24) & 0x80u;
  float a = fabsf(x);
  if (a < 0.001953125f) return s;
  if (a >= 240.f) return s | 0x7Eu;
  if (a < 0.015625f) {
    int m = (int)(a*512.f + 0.5f); if(m>7) m=7;
    return s | (unsigned)m;
  }
  int e = (int)((v.u >> 23) & 0xff) - 127;
  unsigned mant = (v.u >> 20) & 0x7u;
  unsigned rest = v.u & 0xFFFFFu;
  if (rest > 0x80000u || (rest == 0x80000u && (mant&1u))) mant++;
  unsigned ee = (unsigned)(e + 7);
  if (mant == 8u){ mant = 0u; ee++; }
  return s | (ee<<3) | mant;
}
template<bool HI>
static __device__ __forceinline__ unsigned pk8(float a, float b, unsigned old){
#if __has_builtin(__builtin_amdgcn_cvt_pk_fp8_f32)
  return __builtin_amdgcn_cvt_pk_fp8_f32(a, b, old, HI);
#else
  unsigned p = sw_fp8(a) | (sw_fp8(b)<<8);
  return HI ? ((old & 0x0000FFFFu) | (p<<16)) : ((old & 0xFFFF0000u) | p);
#endif
}

typedef const __attribute__((address_space(1))) unsigned int gu32;
typedef __attribute__((address_space(3))) unsigned int lu32;
#define GLL16(gp, lp) __builtin_amdgcn_global_load_lds((gu32*)(gp), (lu32*)(lp), 16, 0, 0)

// ---------------- weight conversion fp32 -> bf16 ----------------
__global__ void cvt_w_kernel(const float* w0,const float* w1,const float* w2,const float* w3,
                             const float* w4,const float* w5,const float* w6,const float* w7,
                             unsigned short* dst){
  int w = blockIdx.y;
  const float* src;
  switch(w){
    case 0: src=w0; break; case 1: src=w1; break; case 2: src=w2; break; case 3: src=w3; break;
    case 4: src=w4; break; case 5: src=w5; break; case 6: src=w6; break; default: src=w7; break;
  }
  int i = blockIdx.x*256 + threadIdx.x;
  float v = src[i];
  if(w==0 || w==4 || w==1 || w==5) v *= 0.32267249f;   // sqrt(log2(e)/sqrt(192))
  dst[(size_t)w*36864 + i] = f2bf(v);
}

// ---------------- fused QKV projection ----------------
// Outputs: Q8,K8 fp8 [row][192] bytes; V bf16 TRANSPOSED [b][d][S].
__global__ __launch_bounds__(256) void proj_kernel(
    const float* __restrict__ x, const unsigned short* __restrict__ Wb,
    unsigned char* __restrict__ QK8, unsigned short* __restrict__ V16)
{
  __shared__ __align__(16) unsigned short Vstage[192*72];   // 27.6 KB
  const size_t MDB = (size_t)M_*D_;
  const size_t MD  = (size_t)M_*D_;
  int tid = threadIdx.x;
  int wid = tid>>6, lane = tid&63;
  int lr = lane&15, lg = lane>>4, kb = lg*8;
  int m0 = blockIdx.x*64 + wid*16;
  int row = m0 + lr;

  v8s a[6];
  #pragma unroll
  for(int c=0;c<6;c++){
    const float* xp = &x[(size_t)row*D_ + c*32 + kb];
    float4 f0 = *(const float4*)xp;
    float4 f1 = *(const float4*)(xp+4);
    v8s t;
    t[0]=(short)f2bf(f0.x); t[1]=(short)f2bf(f0.y); t[2]=(short)f2bf(f0.z); t[3]=(short)f2bf(f0.w);
    t[4]=(short)f2bf(f1.x); t[5]=(short)f2bf(f1.y); t[6]=(short)f2bf(f1.z); t[7]=(short)f2bf(f1.w);
    a[c]=t;
  }
  int bidx = m0 / S_;
  int sb   = (blockIdx.x*64) % S_;
  int sloc = wid*16 + lg*4;

  for(int path=0; path<2; path++){
    unsigned char* dstQ8 = QK8 + (size_t)path*2*MDB;
    for(int which=0; which<2; which++){
      const unsigned short* W = Wb + (size_t)(path*4 + which)*36864;
      unsigned char* dst = which==0 ? dstQ8 : dstQ8 + MDB;
      #pragma unroll
      for(int nt=0; nt<12; nt++){
        v4f acc = {0.f,0.f,0.f,0.f};
        int n = nt*16 + lr;
        #pragma unroll
        for(int c=0;c<6;c++){
          v8s bfr = *(const v8s*)&W[(size_t)n*D_ + c*32 + kb];
          acc = __builtin_amdgcn_mfma_f32_16x16x32_bf16(a[c], bfr, acc, 0,0,0);
        }
        int col = nt*16 + lr;
        int r0 = m0 + lg*4;
        #pragma unroll
        for(int r=0;r<4;r++){
          unsigned p = pk8<false>(acc[r], 0.f, 0u);
          dst[(size_t)(r0+r)*D_ + col] = (unsigned char)(p & 0xFF);
        }
      }
    }
    // V -> bf16 LDS transpose stage -> coalesced stores
    {
      const unsigned short* W = Wb + (size_t)(path*4 + 2)*36864;
      #pragma unroll
      for(int nt=0; nt<12; nt++){
        v4f acc = {0.f,0.f,0.f,0.f};
        int n = nt*16 + lr;
        #pragma unroll
        for(int c=0;c<6;c++){
          v8s bfr = *(const v8s*)&W[(size_t)n*D_ + c*32 + kb];
          acc = __builtin_amdgcn_mfma_f32_16x16x32_bf16(a[c], bfr, acc, 0,0,0);
        }
        int col = nt*16 + lr;
        v4us pk;
        pk[0]=f2bf(acc[0]); pk[1]=f2bf(acc[1]); pk[2]=f2bf(acc[2]); pk[3]=f2bf(acc[3]);
        *(v4us*)&Vstage[col*72 + sloc] = pk;
      }
      __syncthreads();
      unsigned short* dstV = V16 + (size_t)path*MD;
      size_t vg = (size_t)bidx*D_*S_ + sb;
      #pragma unroll
      for(int j=0;j<6;j++){
        int i = tid + j*256;
        int d = i>>3, s8 = (i&7)*8;
        *(v8s*)&dstV[vg + (size_t)d*S_ + s8] = *(const v8s*)&Vstage[d*72 + s8];
      }
      __syncthreads();
    }
  }
}

// ---------------- flash attention: fp8 QK + bf16 PV, 8 waves x 16 q ---------
// grid (32,8,2) XCD-remapped, 512 thr. Full-K (128 tiles). oacc halves to 48
// regs -> ~110 unified/thread -> TRUE 4 waves/SIMD (round-22 lesson: acc
// registers count; 32q/wave's 180/thread caps at 2 waves forever).
// K fp8: reg-staged by waves 0-3 into 200B-stride rows (4-lane/slot uniform,
// conflict-floor). V bf16: DMA by waves 4-7, swizzled (round-17, 0 conflicts).
// 1-tile pipeline: QK(t) -> issue(t+1) -> PV(t-1) -> softmax(t) -> kwrite.
#define KSTR8 200

__global__ __launch_bounds__(512,4) void attn_kernel(
    const unsigned char* __restrict__ QK8,
    const unsigned short* __restrict__ V16,
    unsigned short* __restrict__ Ob)
{
  __shared__ __align__(16) unsigned char  KL[2][32*KSTR8];   // 12.5 KB
  __shared__ __align__(16) unsigned short VL[3][192*32];     // 36 KB (48.5 KB)

  int flat = blockIdx.x + 32*blockIdx.y + 256*blockIdx.z;
  int w = (flat&7)*64 + (flat>>3);   // bijective on [0,512)
  int qi = w & 31;
  int b  = (w>>5) & 7;
  int z  = w>>8;

  const size_t MDB = (size_t)M_*D_;
  const unsigned char* Q8 = QK8 + (size_t)z*2*MDB;
  const unsigned char* K8 = Q8 + MDB;
  const unsigned short* Vt = V16 + (size_t)z*MDB;
  unsigned short* O = Ob + (size_t)z*MDB;

  int q0 = qi*128;
  int tid = threadIdx.x, wid=tid>>6, lane=tid&63;
  int lr = lane&15, lg = lane>>4;
  size_t bK = (size_t)b*S_*D_;        // bytes (fp8)
  size_t bV = (size_t)b*D_*S_;        // shorts
  int qrow0 = q0 + wid*16;

  // staging split: waves 0-3 = K (reg-staged, 24B/thread), waves 4-7 = V (DMA)
  bool isK = wid < 4;
  int kt256 = tid & 255;
  int ksR = kt256>>3, ksC = (kt256&7)*24;
  int kLds = ksR*KSTR8 + ksC;
  int voff[3], vLds[3];
  #pragma unroll
  for(int j=0;j<3;j++){
    int i = (tid & 255) + j*256;                 // 0..767 chunks of 16B
    int vrow = i>>2, vin = (i&3)*16;
    voff[j] = vrow*4096 + ((vin ^ (((vrow>>1)&3)<<4))>>1);   // shorts
    vLds[j] = i*16;                              // bytes, linear
  }
  int vro = ((lg*16) ^ (((lr>>1)&3)<<4)) >> 1;   // shorts

  long qf8[6];
  {
    const unsigned char* qp = Q8 + bK + (size_t)(qrow0 + lr)*D_;
    #pragma unroll
    for(int c=0;c<6;c++) qf8[c] = *(const long*)(qp + c*32 + lg*8);
  }
  float lsum = 0.f;
  v4f oacc[12];
  #pragma unroll
  for(int e=0;e<12;e++) oacc[e] = (v4f){0.f,0.f,0.f,0.f};

  ull k0, k1, k2;
  auto kissue = [&](int t){
    if(isK){
      const unsigned char* kg = K8 + bK + (size_t)t*6144 + ksR*192 + ksC;
      k0 = *(const ull*)(kg);
      k1 = *(const ull*)(kg+8);
      k2 = *(const ull*)(kg+16);
    }
  };
  auto kwrite = [&](int buf){
    if(isK){
      unsigned char* d = &KL[buf][kLds];
      *(ull*)(d)    = k0;
      *(ull*)(d+8)  = k1;
      *(ull*)(d+16) = k2;
    }
  };
  auto vissue = [&](int t, int buf){
    if(!isK){
      const unsigned short* vg = Vt + bV + (size_t)t*32;
      #pragma unroll
      for(int j=0;j<3;j++) GLL16(vg + voff[j], ((unsigned char*)&VL[buf][0]) + vLds[j]);
    }
  };
  auto do_qk = [&](int kcur, v4f sacc[2]){
    __builtin_amdgcn_s_setprio(1);
    #pragma unroll
    for(int ct=0; ct<2; ct++){
      v4f s = {0.f,0.f,0.f,0.f};
      const unsigned char* rb = &KL[kcur][(ct*16+lr)*KSTR8];
      #pragma unroll
      for(int c=0;c<6;c++){
        long kf8 = *(const long*)(rb + c*32 + lg*8);
        s = __builtin_amdgcn_mfma_f32_16x16x32_fp8_fp8(kf8, qf8[c], s, 0,0,0);
      }
      sacc[ct]=s;
    }
    __builtin_amdgcn_s_setprio(0);
  };
  auto do_softmax = [&](v4f sacc[2], v8s& pa){
    float p00=fexp2(sacc[0][0]), p01=fexp2(sacc[0][1]);
    float p02=fexp2(sacc[0][2]), p03=fexp2(sacc[0][3]);
    float p10=fexp2(sacc[1][0]), p11=fexp2(sacc[1][1]);
    float p12=fexp2(sacc[1][2]), p13=fexp2(sacc[1][3]);
    lsum += ((p00+p01)+(p02+p03)) + ((p10+p11)+(p12+p13));
    unsigned X0=cvtpk(p00,p01), X1=cvtpk(p02,p03);
    unsigned Y0=cvtpk(p10,p11), Y1=cvtpk(p12,p13);
    asm("v_permlane32_swap_b32 %0, %1" : "+v"(Y0), "+v"(X0));
    asm("v_permlane32_swap_b32 %0, %1" : "+v"(Y1), "+v"(X1));
    asm("v_permlane16_swap_b32 %0, %1" : "+v"(Y0), "+v"(X0));
    asm("v_permlane16_swap_b32 %0, %1" : "+v"(Y1), "+v"(X1));
    union{ v8s s; unsigned w[4]; } u;
    u.w[0] = X0;  u.w[1] = X1;  u.w[2] = Y0;  u.w[3] = Y1;
    pa = u.s;
  };
  auto do_pv = [&](int vcur, v8s pa){
    __builtin_amdgcn_s_setprio(1);
    #pragma unroll
    for(int e=0;e<12;e++){
      v8s vbf = *(const v8s*)&VL[vcur][(e*16+lr)*32 + vro];
      oacc[e] = __builtin_amdgcn_mfma_f32_16x16x32_bf16(pa, vbf, oacc[e], 0,0,0);
    }
    __builtin_amdgcn_s_setprio(0);
  };

  // prologue: tile 0 -> K0/V0
  kissue(0);
  vissue(0, 0);
  kwrite(0);
  asm volatile("s_waitcnt vmcnt(0)" ::: "memory");
  __syncthreads();

  v8s pa_prev;
  {
    v4f sacc[2];
    do_qk(0, sacc);
    kissue(1);
    vissue(1, 1);
    __builtin_amdgcn_sched_barrier(0);
    do_softmax(sacc, pa_prev);
    kwrite(1);
    asm volatile("s_waitcnt vmcnt(0)" ::: "memory");
    __syncthreads();
  }

  for(int t=1; t<128; t++){
    v4f sacc[2];
    do_qk(t&1, sacc);                      // tile t (staged last iter)
    if(t<127){ kissue(t+1); vissue(t+1, (t+1)%3); }
    __builtin_amdgcn_sched_barrier(0);
    do_pv((t-1)%3, pa_prev);               // PV(t-1): independent of QK(t)
    do_softmax(sacc, pa_prev);             // overwrites pa_prev after use
    if(t<127) kwrite((t+1)&1);
    asm volatile("s_waitcnt vmcnt(0)" ::: "memory");
    __syncthreads();
  }
  do_pv(127%3, pa_prev);

  // epilogue: per-lane sums (q-row = lr) -> row inverses -> O write (bf16)
  float ps = lsum;
  ps += __shfl_xor(ps, 16);
  ps += __shfl_xor(ps, 32);
  float iv = 1.0f/ps;                      // inv for q-row = lr
  float invr[4];
  #pragma unroll
  for(int r=0;r<4;r++) invr[r] = __shfl(iv, lg*4+r, 16);
  size_t orow0 = ((size_t)b*S_ + qrow0 + lg*4)*D_;
  #pragma unroll
  for(int e=0;e<12;e++){
    #pragma unroll
    for(int r=0;r<4;r++){
      O[orow0 + (size_t)r*D_ + e*16 + lr] = f2bf(oacc[e][r]*invr[r]);
    }
  }
}

// ---------------- final: R = O @ Wo^T (both), combine, column fixes ---------
__global__ __launch_bounds__(256) void final_kernel(
  const float* __restrict__ x,
  const unsigned short* __restrict__ Or,
  const unsigned short* __restrict__ Ow,
  const unsigned short* __restrict__ WoR,
  const unsigned short* __restrict__ WoW,
  float* __restrict__ out)
{
  int tid=threadIdx.x, wid=tid>>6, lane=tid&63;
  int lr=lane&15, lg=lane>>4, kb=lg*8;
  int m0 = blockIdx.x*64 + wid*16;
  int arow = m0 + lr;
  v8s ar[6], aw[6];
  #pragma unroll
  for(int c=0;c<6;c++){
    ar[c] = *(const v8s*)&Or[(size_t)arow*D_ + c*32 + kb];
    aw[c] = *(const v8s*)&Ow[(size_t)arow*D_ + c*32 + kb];
  }
  int bidx = m0 / S_;
  float rf = x[(size_t)bidx*S_*D_ + 156];
  float wf = x[(size_t)bidx*S_*D_ + 157];
  #pragma unroll
  for(int nt=0; nt<12; nt++){
    v4f accR={0.f,0.f,0.f,0.f}, accW={0.f,0.f,0.f,0.f};
    int n = nt*16 + lr;
    #pragma unroll
    for(int c=0;c<6;c++){
      v8s br = *(const v8s*)&WoR[(size_t)n*D_ + c*32 + kb];
      accR = __builtin_amdgcn_mfma_f32_16x16x32_bf16(ar[c], br, accR,0,0,0);
      v8s bw = *(const v8s*)&WoW[(size_t)n*D_ + c*32 + kb];
      accW = __builtin_amdgcn_mfma_f32_16x16x32_bf16(aw[c], bw, accW,0,0,0);
    }
    #pragma unroll
    for(int r=0;r<4;r++){
      int row = m0 + lg*4 + r;
      int col = nt*16 + lr;
      float xv = x[(size_t)row*D_ + col];
      float val = xv + rf*(accR[r]-xv) + wf*(accW[r]-xv);
      if(col==156||col==157) val = 0.f;
      else if(col==158) val = rf+wf;
      out[(size_t)row*D_ + col] = val;
    }
  }
}

extern "C" void kernel_launch(void* const* d_in, const int* in_sizes, int n_in,
                              void* d_out, int out_size, void* d_ws, size_t ws_size,
                              hipStream_t stream) {
  const float* x = (const float*)d_in[0];
  char* wsb = (char*)d_ws;
  const size_t WSZ = 36864;
  const size_t MDB = (size_t)M_*D_;
  unsigned short* Wb  = (unsigned short*)wsb;                        // 0.59 MB
  unsigned char*  QK8 = (unsigned char*)(wsb + 8*WSZ*2);             // 25.2 MB
  unsigned short* V16 = (unsigned short*)(wsb + 8*WSZ*2 + 4*MDB);    // 25.2 MB (shorts)
  unsigned short* Ob  = V16 + 2*MDB;                                 // 25.2 MB (shorts)

  cvt_w_kernel<<<dim3(144,8),256,0,stream>>>(
      (const float*)d_in[1],(const float*)d_in[2],(const float*)d_in[3],(const float*)d_in[4],
      (const float*)d_in[5],(const float*)d_in[6],(const float*)d_in[7],(const float*)d_in[8], Wb);

  proj_kernel<<<512,256,0,stream>>>(x, Wb, QK8, V16);
  attn_kernel<<<dim3(32,8,2),512,0,stream>>>(QK8, V16, Ob);
  final_kernel<<<512,256,0,stream>>>(x, Ob, Ob + MDB,
                                     Wb+3*WSZ, Wb+7*WSZ, (float*)d_out);
}

// Round 24
// 320.452 us; speedup vs baseline: 3.3306x; 1.0458x over previous
//
#include <hip/hip_runtime.h>
#include <stdint.h>

#define B_ 8
#define S_ 4096
#define D_ 192
#define M_ (B_*S_)

typedef short v8s __attribute__((ext_vector_type(8)));
typedef float v4f __attribute__((ext_vector_type(4)));
typedef unsigned short v4us __attribute__((ext_vector_type(4)));
typedef unsigned long long ull;

static __device__ __forceinline__ unsigned short f2bf(float f){
  union{float f; unsigned u;} v; v.f=f;
  unsigned u = v.u;
  unsigned r = (u + 0x7fffu + ((u>>16)&1u))>>16;
  return (unsigned short)r;
}
static __device__ __forceinline__ float fexp2(float x){
  return __builtin_amdgcn_exp2f(x);
}
static __device__ __forceinline__ unsigned cvtpk(float lo, float hi){
  unsigned r;
  asm("v_cvt_pk_bf16_f32 %0, %1, %2" : "=v"(r) : "v"(lo), "v"(hi));
  return r;
}

// ---- fp8 e4m3fn pack ----
static __device__ __forceinline__ unsigned sw_fp8(float x){
  union{float f; unsigned u;} v; v.f = x;
  unsigned s = (v.u >> 24) & 0x80u;
  float a = fabsf(x);
  if (a < 0.001953125f) return s;
  if (a >= 240.f) return s | 0x7Eu;
  if (a < 0.015625f) {
    int m = (int)(a*512.f + 0.5f); if(m>7) m=7;
    return s | (unsigned)m;
  }
  int e = (int)((v.u >> 23) & 0xff) - 127;
  unsigned mant = (v.u >> 20) & 0x7u;
  unsigned rest = v.u & 0xFFFFFu;
  if (rest > 0x80000u || (rest == 0x80000u && (mant&1u))) mant++;
  unsigned ee = (unsigned)(e + 7);
  if (mant == 8u){ mant = 0u; ee++; }
  return s | (ee<<3) | mant;
}
template<bool HI>
static __device__ __forceinline__ unsigned pk8(float a, float b, unsigned old){
#if __has_builtin(__builtin_amdgcn_cvt_pk_fp8_f32)
  return __builtin_amdgcn_cvt_pk_fp8_f32(a, b, old, HI);
#else
  unsigned p = sw_fp8(a) | (sw_fp8(b)<<8);
  return HI ? ((old & 0x0000FFFFu) | (p<<16)) : ((old & 0xFFFF0000u) | p);
#endif
}

typedef const __attribute__((address_space(1))) unsigned int gu32;
typedef __attribute__((address_space(3))) unsigned int lu32;
#define GLL16(gp, lp) __builtin_amdgcn_global_load_lds((gu32*)(gp), (lu32*)(lp), 16, 0, 0)

// ---------------- weight conversion fp32 -> bf16 ----------------
__global__ void cvt_w_kernel(const float* w0,const float* w1,const float* w2,const float* w3,
                             const float* w4,const float* w5,const float* w6,const float* w7,
                             unsigned short* dst){
  int w = blockIdx.y;
  const float* src;
  switch(w){
    case 0: src=w0; break; case 1: src=w1; break; case 2: src=w2; break; case 3: src=w3; break;
    case 4: src=w4; break; case 5: src=w5; break; case 6: src=w6; break; default: src=w7; break;
  }
  int i = blockIdx.x*256 + threadIdx.x;
  float v = src[i];
  if(w==0 || w==4 || w==1 || w==5) v *= 0.32267249f;   // sqrt(log2(e)/sqrt(192))
  dst[(size_t)w*36864 + i] = f2bf(v);
}

// ---------------- fused QKV projection, split by path ----------------
// grid dim3(512,2) = 1024 blocks -> 4 blocks/CU (was 2: latency-bound).
// Outputs: Q8,K8 fp8 [row][192] bytes; V bf16 TRANSPOSED [b][d][S].
__global__ __launch_bounds__(256) void proj_kernel(
    const float* __restrict__ x, const unsigned short* __restrict__ Wb,
    unsigned char* __restrict__ QK8, unsigned short* __restrict__ V16)
{
  __shared__ __align__(16) unsigned short Vstage[192*72];   // 27.6 KB
  const size_t MDB = (size_t)M_*D_;
  const size_t MD  = (size_t)M_*D_;
  int path = blockIdx.y;
  int tid = threadIdx.x;
  int wid = tid>>6, lane = tid&63;
  int lr = lane&15, lg = lane>>4, kb = lg*8;
  int m0 = blockIdx.x*64 + wid*16;
  int row = m0 + lr;

  v8s a[6];
  #pragma unroll
  for(int c=0;c<6;c++){
    const float* xp = &x[(size_t)row*D_ + c*32 + kb];
    float4 f0 = *(const float4*)xp;
    float4 f1 = *(const float4*)(xp+4);
    v8s t;
    t[0]=(short)f2bf(f0.x); t[1]=(short)f2bf(f0.y); t[2]=(short)f2bf(f0.z); t[3]=(short)f2bf(f0.w);
    t[4]=(short)f2bf(f1.x); t[5]=(short)f2bf(f1.y); t[6]=(short)f2bf(f1.z); t[7]=(short)f2bf(f1.w);
    a[c]=t;
  }
  int bidx = m0 / S_;
  int sb   = (blockIdx.x*64) % S_;
  int sloc = wid*16 + lg*4;

  unsigned char* dstQ8 = QK8 + (size_t)path*2*MDB;
  for(int which=0; which<2; which++){
    const unsigned short* W = Wb + (size_t)(path*4 + which)*36864;
    unsigned char* dst = which==0 ? dstQ8 : dstQ8 + MDB;
    #pragma unroll
    for(int nt=0; nt<12; nt++){
      v4f acc = {0.f,0.f,0.f,0.f};
      int n = nt*16 + lr;
      #pragma unroll
      for(int c=0;c<6;c++){
        v8s bfr = *(const v8s*)&W[(size_t)n*D_ + c*32 + kb];
        acc = __builtin_amdgcn_mfma_f32_16x16x32_bf16(a[c], bfr, acc, 0,0,0);
      }
      int col = nt*16 + lr;
      int r0 = m0 + lg*4;
      #pragma unroll
      for(int r=0;r<4;r++){
        unsigned p = pk8<false>(acc[r], 0.f, 0u);
        dst[(size_t)(r0+r)*D_ + col] = (unsigned char)(p & 0xFF);
      }
    }
  }
  // V -> bf16 LDS transpose stage -> coalesced stores
  {
    const unsigned short* W = Wb + (size_t)(path*4 + 2)*36864;
    #pragma unroll
    for(int nt=0; nt<12; nt++){
      v4f acc = {0.f,0.f,0.f,0.f};
      int n = nt*16 + lr;
      #pragma unroll
      for(int c=0;c<6;c++){
        v8s bfr = *(const v8s*)&W[(size_t)n*D_ + c*32 + kb];
        acc = __builtin_amdgcn_mfma_f32_16x16x32_bf16(a[c], bfr, acc, 0,0,0);
      }
      int col = nt*16 + lr;
      v4us pk;
      pk[0]=f2bf(acc[0]); pk[1]=f2bf(acc[1]); pk[2]=f2bf(acc[2]); pk[3]=f2bf(acc[3]);
      *(v4us*)&Vstage[col*72 + sloc] = pk;
    }
    __syncthreads();
    unsigned short* dstV = V16 + (size_t)path*MD;
    size_t vg = (size_t)bidx*D_*S_ + sb;
    #pragma unroll
    for(int j=0;j<6;j++){
      int i = tid + j*256;
      int d = i>>3, s8 = (i&7)*8;
      *(v8s*)&dstV[vg + (size_t)d*S_ + s8] = *(const v8s*)&Vstage[d*72 + s8];
    }
  }
}

// ---------------- flash attention: fp8 QK + bf16 PV, 8 waves x 16 q ---------
// (unchanged from round 23: 184.5 us, Occ 40%, MfmaUtil 52%)
#define KSTR8 200

__global__ __launch_bounds__(512,4) void attn_kernel(
    const unsigned char* __restrict__ QK8,
    const unsigned short* __restrict__ V16,
    unsigned short* __restrict__ Ob)
{
  __shared__ __align__(16) unsigned char  KL[2][32*KSTR8];   // 12.5 KB
  __shared__ __align__(16) unsigned short VL[3][192*32];     // 36 KB (48.5 KB)

  int flat = blockIdx.x + 32*blockIdx.y + 256*blockIdx.z;
  int w = (flat&7)*64 + (flat>>3);   // bijective on [0,512)
  int qi = w & 31;
  int b  = (w>>5) & 7;
  int z  = w>>8;

  const size_t MDB = (size_t)M_*D_;
  const unsigned char* Q8 = QK8 + (size_t)z*2*MDB;
  const unsigned char* K8 = Q8 + MDB;
  const unsigned short* Vt = V16 + (size_t)z*MDB;
  unsigned short* O = Ob + (size_t)z*MDB;

  int q0 = qi*128;
  int tid = threadIdx.x, wid=tid>>6, lane=tid&63;
  int lr = lane&15, lg = lane>>4;
  size_t bK = (size_t)b*S_*D_;        // bytes (fp8)
  size_t bV = (size_t)b*D_*S_;        // shorts
  int qrow0 = q0 + wid*16;

  bool isK = wid < 4;
  int kt256 = tid & 255;
  int ksR = kt256>>3, ksC = (kt256&7)*24;
  int kLds = ksR*KSTR8 + ksC;
  int voff[3], vLds[3];
  #pragma unroll
  for(int j=0;j<3;j++){
    int i = (tid & 255) + j*256;
    int vrow = i>>2, vin = (i&3)*16;
    voff[j] = vrow*4096 + ((vin ^ (((vrow>>1)&3)<<4))>>1);
    vLds[j] = i*16;
  }
  int vro = ((lg*16) ^ (((lr>>1)&3)<<4)) >> 1;

  long qf8[6];
  {
    const unsigned char* qp = Q8 + bK + (size_t)(qrow0 + lr)*D_;
    #pragma unroll
    for(int c=0;c<6;c++) qf8[c] = *(const long*)(qp + c*32 + lg*8);
  }
  float lsum = 0.f;
  v4f oacc[12];
  #pragma unroll
  for(int e=0;e<12;e++) oacc[e] = (v4f){0.f,0.f,0.f,0.f};

  ull k0, k1, k2;
  auto kissue = [&](int t){
    if(isK){
      const unsigned char* kg = K8 + bK + (size_t)t*6144 + ksR*192 + ksC;
      k0 = *(const ull*)(kg);
      k1 = *(const ull*)(kg+8);
      k2 = *(const ull*)(kg+16);
    }
  };
  auto kwrite = [&](int buf){
    if(isK){
      unsigned char* d = &KL[buf][kLds];
      *(ull*)(d)    = k0;
      *(ull*)(d+8)  = k1;
      *(ull*)(d+16) = k2;
    }
  };
  auto vissue = [&](int t, int buf){
    if(!isK){
      const unsigned short* vg = Vt + bV + (size_t)t*32;
      #pragma unroll
      for(int j=0;j<3;j++) GLL16(vg + voff[j], ((unsigned char*)&VL[buf][0]) + vLds[j]);
    }
  };
  auto do_qk = [&](int kcur, v4f sacc[2]){
    __builtin_amdgcn_s_setprio(1);
    #pragma unroll
    for(int ct=0; ct<2; ct++){
      v4f s = {0.f,0.f,0.f,0.f};
      const unsigned char* rb = &KL[kcur][(ct*16+lr)*KSTR8];
      #pragma unroll
      for(int c=0;c<6;c++){
        long kf8 = *(const long*)(rb + c*32 + lg*8);
        s = __builtin_amdgcn_mfma_f32_16x16x32_fp8_fp8(kf8, qf8[c], s, 0,0,0);
      }
      sacc[ct]=s;
    }
    __builtin_amdgcn_s_setprio(0);
  };
  auto do_softmax = [&](v4f sacc[2], v8s& pa){
    float p00=fexp2(sacc[0][0]), p01=fexp2(sacc[0][1]);
    float p02=fexp2(sacc[0][2]), p03=fexp2(sacc[0][3]);
    float p10=fexp2(sacc[1][0]), p11=fexp2(sacc[1][1]);
    float p12=fexp2(sacc[1][2]), p13=fexp2(sacc[1][3]);
    lsum += ((p00+p01)+(p02+p03)) + ((p10+p11)+(p12+p13));
    unsigned X0=cvtpk(p00,p01), X1=cvtpk(p02,p03);
    unsigned Y0=cvtpk(p10,p11), Y1=cvtpk(p12,p13);
    asm("v_permlane32_swap_b32 %0, %1" : "+v"(Y0), "+v"(X0));
    asm("v_permlane32_swap_b32 %0, %1" : "+v"(Y1), "+v"(X1));
    asm("v_permlane16_swap_b32 %0, %1" : "+v"(Y0), "+v"(X0));
    asm("v_permlane16_swap_b32 %0, %1" : "+v"(Y1), "+v"(X1));
    union{ v8s s; unsigned w[4]; } u;
    u.w[0] = X0;  u.w[1] = X1;  u.w[2] = Y0;  u.w[3] = Y1;
    pa = u.s;
  };
  auto do_pv = [&](int vcur, v8s pa){
    __builtin_amdgcn_s_setprio(1);
    #pragma unroll
    for(int e=0;e<12;e++){
      v8s vbf = *(const v8s*)&VL[vcur][(e*16+lr)*32 + vro];
      oacc[e] = __builtin_amdgcn_mfma_f32_16x16x32_bf16(pa, vbf, oacc[e], 0,0,0);
    }
    __builtin_amdgcn_s_setprio(0);
  };

  kissue(0);
  vissue(0, 0);
  kwrite(0);
  asm volatile("s_waitcnt vmcnt(0)" ::: "memory");
  __syncthreads();

  v8s pa_prev;
  {
    v4f sacc[2];
    do_qk(0, sacc);
    kissue(1);
    vissue(1, 1);
    __builtin_amdgcn_sched_barrier(0);
    do_softmax(sacc, pa_prev);
    kwrite(1);
    asm volatile("s_waitcnt vmcnt(0)" ::: "memory");
    __syncthreads();
  }

  for(int t=1; t<128; t++){
    v4f sacc[2];
    do_qk(t&1, sacc);
    if(t<127){ kissue(t+1); vissue(t+1, (t+1)%3); }
    __builtin_amdgcn_sched_barrier(0);
    do_pv((t-1)%3, pa_prev);
    do_softmax(sacc, pa_prev);
    if(t<127) kwrite((t+1)&1);
    asm volatile("s_waitcnt vmcnt(0)" ::: "memory");
    __syncthreads();
  }
  do_pv(127%3, pa_prev);

  float ps = lsum;
  ps += __shfl_xor(ps, 16);
  ps += __shfl_xor(ps, 32);
  float iv = 1.0f/ps;
  float invr[4];
  #pragma unroll
  for(int r=0;r<4;r++) invr[r] = __shfl(iv, lg*4+r, 16);
  size_t orow0 = ((size_t)b*S_ + qrow0 + lg*4)*D_;
  #pragma unroll
  for(int e=0;e<12;e++){
    #pragma unroll
    for(int r=0;r<4;r++){
      O[orow0 + (size_t)r*D_ + e*16 + lr] = f2bf(oacc[e][r]*invr[r]);
    }
  }
}

// ---------------- final: split by column-half, 4 blocks/CU ----------------
// grid dim3(512,2). Block computes out cols [96h, 96h+96) for its 64 rows.
__global__ __launch_bounds__(256) void final_kernel(
  const float* __restrict__ x,
  const unsigned short* __restrict__ Or,
  const unsigned short* __restrict__ Ow,
  const unsigned short* __restrict__ WoR,
  const unsigned short* __restrict__ WoW,
  float* __restrict__ out)
{
  int halfn = blockIdx.y;
  int tid=threadIdx.x, wid=tid>>6, lane=tid&63;
  int lr=lane&15, lg=lane>>4, kb=lg*8;
  int m0 = blockIdx.x*64 + wid*16;
  int arow = m0 + lr;
  v8s ar[6], aw[6];
  #pragma unroll
  for(int c=0;c<6;c++){
    ar[c] = *(const v8s*)&Or[(size_t)arow*D_ + c*32 + kb];
    aw[c] = *(const v8s*)&Ow[(size_t)arow*D_ + c*32 + kb];
  }
  int bidx = m0 / S_;
  float rf = x[(size_t)bidx*S_*D_ + 156];
  float wf = x[(size_t)bidx*S_*D_ + 157];
  #pragma unroll
  for(int ntl=0; ntl<6; ntl++){
    int nt = halfn*6 + ntl;
    v4f accR={0.f,0.f,0.f,0.f}, accW={0.f,0.f,0.f,0.f};
    int n = nt*16 + lr;
    #pragma unroll
    for(int c=0;c<6;c++){
      v8s br = *(const v8s*)&WoR[(size_t)n*D_ + c*32 + kb];
      accR = __builtin_amdgcn_mfma_f32_16x16x32_bf16(ar[c], br, accR,0,0,0);
      v8s bw = *(const v8s*)&WoW[(size_t)n*D_ + c*32 + kb];
      accW = __builtin_amdgcn_mfma_f32_16x16x32_bf16(aw[c], bw, accW,0,0,0);
    }
    #pragma unroll
    for(int r=0;r<4;r++){
      int row = m0 + lg*4 + r;
      int col = nt*16 + lr;
      float xv = x[(size_t)row*D_ + col];
      float val = xv + rf*(accR[r]-xv) + wf*(accW[r]-xv);
      if(col==156||col==157) val = 0.f;
      else if(col==158) val = rf+wf;
      out[(size_t)row*D_ + col] = val;
    }
  }
}

extern "C" void kernel_launch(void* const* d_in, const int* in_sizes, int n_in,
                              void* d_out, int out_size, void* d_ws, size_t ws_size,
                              hipStream_t stream) {
  const float* x = (const float*)d_in[0];
  char* wsb = (char*)d_ws;
  const size_t WSZ = 36864;
  const size_t MDB = (size_t)M_*D_;
  unsigned short* Wb  = (unsigned short*)wsb;                        // 0.59 MB
  unsigned char*  QK8 = (unsigned char*)(wsb + 8*WSZ*2);             // 25.2 MB
  unsigned short* V16 = (unsigned short*)(wsb + 8*WSZ*2 + 4*MDB);    // 25.2 MB (shorts)
  unsigned short* Ob  = V16 + 2*MDB;                                 // 25.2 MB (shorts)

  cvt_w_kernel<<<dim3(144,8),256,0,stream>>>(
      (const float*)d_in[1],(const float*)d_in[2],(const float*)d_in[3],(const float*)d_in[4],
      (const float*)d_in[5],(const float*)d_in[6],(const float*)d_in[7],(const float*)d_in[8], Wb);

  proj_kernel<<<dim3(512,2),256,0,stream>>>(x, Wb, QK8, V16);
  attn_kernel<<<dim3(32,8,2),512,0,stream>>>(QK8, V16, Ob);
  final_kernel<<<dim3(512,2),256,0,stream>>>(x, Ob, Ob + MDB,
                                             Wb+3*WSZ, Wb+7*WSZ, (float*)d_out);
}